// Round 2
// baseline (778.974 us; speedup 1.0000x reference)
//
#include <hip/hip_runtime.h>

#define P_  49152
#define J_  16
#define DL_ 10
#define H_  64
#define O_  (3 * P_)   // 147456 output rows

// ---------------------------------------------------------------------------
// Kernel 1: compute dh[j][h] = relu(w1·feat + b1) - relu(w1·zfeat + b1)
// J*H = 1024 threads, one block. Output: 1024 floats into workspace.
// ---------------------------------------------------------------------------
__global__ __launch_bounds__(1024) void dh_kernel(
    const float* __restrict__ x,        // (J*9,)
    const float* __restrict__ latent,   // (J, DL)
    const float* __restrict__ w1,       // (J, H, 37)
    const float* __restrict__ b1,       // (J, H)
    const int*   __restrict__ nidx,     // (J, 3)
    const float* __restrict__ nmask,    // (J, 3)
    float* __restrict__ dh)             // (J, H) out
{
    __shared__ float feat[J_][37];
    const int tid = threadIdx.x;

    // Fill feat: first 27 entries = masked neighbor gather, last 10 = latent.
    if (tid < J_ * 27) {
        int j = tid / 27, i = tid % 27;
        int k = i / 9, u = i % 9;
        feat[j][i] = x[nidx[j * 3 + k] * 9 + u] * nmask[j * 3 + k];
    } else if (tid >= 512 && tid < 512 + J_ * DL_) {
        int t = tid - 512;
        int j = t / DL_, d = t % DL_;
        feat[j][27 + d] = latent[j * DL_ + d];
    }
    __syncthreads();

    const int j = tid >> 6, h = tid & 63;
    const float* wrow = w1 + (j * H_ + h) * 37;
    float z1 = b1[j * H_ + h];
    float z0 = z1;
#pragma unroll
    for (int i = 0; i < 27; ++i) z1 += feat[j][i] * wrow[i];
#pragma unroll
    for (int i = 27; i < 37; ++i) {
        float t = feat[j][i] * wrow[i];
        z1 += t; z0 += t;
    }
    dh[j * H_ + h] = fmaxf(z1, 0.f) - fmaxf(z0, 0.f);
}

// ---------------------------------------------------------------------------
// Kernel 2: out[r] = iv[r] + 1e-3 * sum_j relu(mask[j, r/3]) * dot(dh[j], w2[j,r,:])
// 256 threads/block. Each 16-lane group owns one row; lane t loads float4
// w2[j][r][4t]. Per-wave global load = contiguous 1 KB (perfect coalescing).
// ---------------------------------------------------------------------------
__global__ __launch_bounds__(256) void out_kernel(
    const float*  __restrict__ w2,        // (J, O, H)
    const float*  __restrict__ mask_param,// (J, P)
    const float*  __restrict__ dh,        // (J, H)
    const float*  __restrict__ iv,        // (P*3,)
    float* __restrict__ out)              // (P*3,)
{
    __shared__ float4 dh4[J_ * 16];       // dh as float4: [j][t]
    const int tid = threadIdx.x;
    dh4[tid] = ((const float4*)dh)[tid];  // 256 float4 = 1024 floats
    __syncthreads();

    const int lane = tid & 63;
    const int wave = tid >> 6;
    const int g = lane >> 4;              // group within wave (0..3)
    const int t = lane & 15;              // lane within group (0..15)
    const int r = blockIdx.x * 16 + wave * 4 + g;   // output row
    const int p = r / 3;                  // vertex index

    const float4* w2v = (const float4*)w2 + (size_t)r * 16 + t;
    const size_t jstride = (size_t)O_ * 16;   // float4 stride per joint

    float lacc = 0.f;
#pragma unroll
    for (int j = 0; j < J_; ++j) {
        float4 w = w2v[j * jstride];
        float4 d = dh4[j * 16 + t];
        float part = w.x * d.x + w.y * d.y + w.z * d.z + w.w * d.w;
        float m = fmaxf(mask_param[j * P_ + p], 0.f);
        lacc += m * part;
    }
    // Reduce across the 16-lane group.
    lacc += __shfl_xor(lacc, 1);
    lacc += __shfl_xor(lacc, 2);
    lacc += __shfl_xor(lacc, 4);
    lacc += __shfl_xor(lacc, 8);

    if (t == 0) out[r] = iv[r] + lacc * 1e-3f;
}

// ---------------------------------------------------------------------------
extern "C" void kernel_launch(void* const* d_in, const int* in_sizes, int n_in,
                              void* d_out, int out_size, void* d_ws, size_t ws_size,
                              hipStream_t stream)
{
    const float* x      = (const float*)d_in[0];
    const float* iv     = (const float*)d_in[1];
    const float* latent = (const float*)d_in[2];
    const float* maskp  = (const float*)d_in[3];
    const float* w1     = (const float*)d_in[4];
    const float* b1     = (const float*)d_in[5];
    const float* w2     = (const float*)d_in[6];
    // d_in[7] = b2 (cancels in corr - corr0), d_in[8]/[9] = neighbor idx/mask
    const int*   nidx   = (const int*)d_in[8];
    const float* nmask  = (const float*)d_in[9];
    float* out = (float*)d_out;
    float* dh  = (float*)d_ws;   // J*H floats = 4 KB

    dh_kernel<<<1, 1024, 0, stream>>>(x, latent, w1, b1, nidx, nmask, dh);
    out_kernel<<<O_ / 16, 256, 0, stream>>>(w2, maskp, dh, iv, out);
}

// Round 4
// 732.955 us; speedup vs baseline: 1.0628x; 1.0628x over previous
//
#include <hip/hip_runtime.h>

#define P_  49152
#define J_  16
#define DL_ 10
#define H_  64
#define O_  (3 * P_)   // 147456 output rows

// ---------------------------------------------------------------------------
// Kernel 1: compute dh[j][h] = relu(w1·feat + b1) - relu(w1·zfeat + b1)
// J*H = 1024 threads, one block. Output: 1024 floats into workspace.
// ---------------------------------------------------------------------------
__global__ __launch_bounds__(1024) void dh_kernel(
    const float* __restrict__ x,        // (J*9,)
    const float* __restrict__ latent,   // (J, DL)
    const float* __restrict__ w1,       // (J, H, 37)
    const float* __restrict__ b1,       // (J, H)
    const int*   __restrict__ nidx,     // (J, 3)
    const float* __restrict__ nmask,    // (J, 3)
    float* __restrict__ dh)             // (J, H) out
{
    __shared__ float feat[J_][37];
    const int tid = threadIdx.x;

    if (tid < J_ * 27) {
        int j = tid / 27, i = tid % 27;
        int k = i / 9, u = i % 9;
        feat[j][i] = x[nidx[j * 3 + k] * 9 + u] * nmask[j * 3 + k];
    } else if (tid >= 512 && tid < 512 + J_ * DL_) {
        int t = tid - 512;
        int j = t / DL_, d = t % DL_;
        feat[j][27 + d] = latent[j * DL_ + d];
    }
    __syncthreads();

    const int j = tid >> 6, h = tid & 63;
    const float* wrow = w1 + (j * H_ + h) * 37;
    float z1 = b1[j * H_ + h];
    float z0 = z1;
#pragma unroll
    for (int i = 0; i < 27; ++i) z1 += feat[j][i] * wrow[i];
#pragma unroll
    for (int i = 27; i < 37; ++i) {
        float t = feat[j][i] * wrow[i];
        z1 += t; z0 += t;
    }
    dh[j * H_ + h] = fmaxf(z1, 0.f) - fmaxf(z0, 0.f);
}

// ---------------------------------------------------------------------------
// Kernel 2: out[r] = iv[r] + 1e-3 * sum_j relu(mask[j, r/3]) * dot(dh[j], w2[j,r,:])
// 16-lane group per output row; lane t loads float4 w2[j][r][4t].
// Mask-sparsity: skip the w2 load entirely when relu(mask[j,p]) == 0 (~50%
// of (j,p)). Branch is uniform within the 16-lane group, exec-masked across
// the wave, so inactive groups fetch nothing -> ~halves w2 HBM traffic.
// ---------------------------------------------------------------------------
__global__ __launch_bounds__(256) void out_kernel(
    const float*  __restrict__ w2,        // (J, O, H)
    const float*  __restrict__ mask_param,// (J, P)
    const float*  __restrict__ dh,        // (J, H)
    const float*  __restrict__ iv,        // (P*3,)
    float* __restrict__ out)              // (P*3,)
{
    __shared__ float4 dh4[J_ * 16];       // dh as float4: [j][t]
    const int tid = threadIdx.x;
    dh4[tid] = ((const float4*)dh)[tid];  // 256 float4 = 1024 floats
    __syncthreads();

    const int lane = tid & 63;
    const int wave = tid >> 6;
    const int g = lane >> 4;              // group within wave (0..3)
    const int t = lane & 15;              // lane within group (0..15)
    const int r = blockIdx.x * 16 + wave * 4 + g;   // output row
    const int p = r / 3;                  // vertex index

    const float4* w2v = (const float4*)w2 + (size_t)r * 16 + t;
    const size_t jstride = (size_t)O_ * 16;   // float4 stride per joint

    // Hoist all 16 mask loads (independent, pipeline together).
    float m[J_];
#pragma unroll
    for (int j = 0; j < J_; ++j)
        m[j] = fmaxf(mask_param[j * P_ + p], 0.f);

    float lacc = 0.f;
#pragma unroll
    for (int j = 0; j < J_; ++j) {
        if (m[j] > 0.f) {                 // group-uniform; skip dead w2 rows
            float4 w = w2v[j * jstride];
            float4 d = dh4[j * 16 + t];
            lacc += m[j] * (w.x * d.x + w.y * d.y + w.z * d.z + w.w * d.w);
        }
    }
    // Reduce across the 16-lane group.
    lacc += __shfl_xor(lacc, 1);
    lacc += __shfl_xor(lacc, 2);
    lacc += __shfl_xor(lacc, 4);
    lacc += __shfl_xor(lacc, 8);

    if (t == 0) out[r] = iv[r] + lacc * 1e-3f;
}

// ---------------------------------------------------------------------------
extern "C" void kernel_launch(void* const* d_in, const int* in_sizes, int n_in,
                              void* d_out, int out_size, void* d_ws, size_t ws_size,
                              hipStream_t stream)
{
    const float* x      = (const float*)d_in[0];
    const float* iv     = (const float*)d_in[1];
    const float* latent = (const float*)d_in[2];
    const float* maskp  = (const float*)d_in[3];
    const float* w1     = (const float*)d_in[4];
    const float* b1     = (const float*)d_in[5];
    const float* w2     = (const float*)d_in[6];
    // d_in[7] = b2 (cancels in corr - corr0), d_in[8]/[9] = neighbor idx/mask
    const int*   nidx   = (const int*)d_in[8];
    const float* nmask  = (const float*)d_in[9];
    float* out = (float*)d_out;
    float* dh  = (float*)d_ws;   // J*H floats = 4 KB

    dh_kernel<<<1, 1024, 0, stream>>>(x, latent, w1, b1, nidx, nmask, dh);
    out_kernel<<<O_ / 16, 256, 0, stream>>>(w2, maskp, dh, iv, out);
}